// Round 5
// baseline (225.352 us; speedup 1.0000x reference)
//
#include <hip/hip_runtime.h>

#define BB 8
#define CC 64
#define HH 112
#define WW 112
#define HWs (HH * WW)                 // 12544
#define KEYN 9

// ---- conv_key geometry ----
#define CK_PX 128
#define CK_TILES (HWs / CK_PX)        // 98
#define CK_NBLK (BB * CK_TILES)       // 784
#define WTS 68                        // Wt row stride (floats): 16B-aligned rows

// ---- fused sampler geometry ----
#define SM_PX 32
#define SM_TILES (HWs / SM_PX)        // 392
#define SM_NBLK (BB * SM_TILES)       // 3136

// fused-kernel LDS float offsets
#define OFF_QIN  0                    // Qin[64][32] (2048); overlaid by OutT[32][69] (2208)
#define OFF_WQ   2208                 // Wq[64][20] (1280)
#define OFF_SB   3488                 // Sb[20]
#define OFF_L    3508                 // L[32][21] (672)
#define OFF_T    4180                 // T[32][9][4] uint2 (2304 floats); even -> 8B aligned
#define SM_LDS   6484                 // 25.9 KB -> 6 blocks/CU

__device__ __forceinline__ float swz1(float v) {
    return __uint_as_float(__builtin_amdgcn_ds_swizzle(__float_as_uint(v), 0x041F));
}
__device__ __forceinline__ float swz2(float v) {
    return __uint_as_float(__builtin_amdgcn_ds_swizzle(__float_as_uint(v), 0x081F));
}

// ---------------------------------------------------------------------------
// conv_key: Kf[b*HW+px][64] = W_refer @ key + b_refer  (pixel-major output)
// 256 thr, 128px x 64out tile; thread = (og=t&7 -> 8 outs, p4=t>>3 -> 4 px).
// Per k: 3 ds_read_b128 -> 32 FMA. ~20 us (latency-tail bound, 3 blocks/CU).
// ---------------------------------------------------------------------------
__global__ __launch_bounds__(256, 3) void conv_key_kernel(
    const float* __restrict__ key, const float* __restrict__ w_refer,
    const float* __restrict__ b_refer, float* __restrict__ Kf)
{
    __shared__ float Xin[64 * CK_PX];   // [k][px]  32 KB
    __shared__ float Wt[64 * WTS];      // [k][o]   17.4 KB

    const int t = threadIdx.x;
    const int blk = blockIdx.x;
    const int b = blk / CK_TILES;
    const int s0 = (blk - b * CK_TILES) * CK_PX;
    const size_t inb = (size_t)b * CC * HWs + s0;

    #pragma unroll
    for (int m = 0; m < 4; ++m) {
        const int f = t + 256 * m;
        const int o = f >> 4;
        const int q = f & 15;
        const float4 wv = *reinterpret_cast<const float4*>(w_refer + o * CC + 4 * q);
        Wt[(4 * q + 0) * WTS + o] = wv.x;
        Wt[(4 * q + 1) * WTS + o] = wv.y;
        Wt[(4 * q + 2) * WTS + o] = wv.z;
        Wt[(4 * q + 3) * WTS + o] = wv.w;
    }
    #pragma unroll
    for (int m = 0; m < 8; ++m) {
        const int f = t + 256 * m;
        const int k = f >> 5;
        const int p8 = f & 31;
        *reinterpret_cast<float4*>(&Xin[k * CK_PX + 4 * p8]) =
            *reinterpret_cast<const float4*>(key + inb + (size_t)k * HWs + 4 * p8);
    }
    __syncthreads();

    const int og = t & 7;
    const int p4 = t >> 3;
    const float4 bias0 = *reinterpret_cast<const float4*>(b_refer + 8 * og);
    const float4 bias1 = *reinterpret_cast<const float4*>(b_refer + 8 * og + 4);
    float4 acc[4][2];
    #pragma unroll
    for (int pi = 0; pi < 4; ++pi) { acc[pi][0] = bias0; acc[pi][1] = bias1; }

    #pragma unroll 4
    for (int k = 0; k < 64; ++k) {
        const float4 a4 = *reinterpret_cast<const float4*>(&Xin[k * CK_PX + 4 * p4]);
        const float4 w0 = *reinterpret_cast<const float4*>(&Wt[k * WTS + 8 * og]);
        const float4 w1 = *reinterpret_cast<const float4*>(&Wt[k * WTS + 8 * og + 4]);
        const float ap[4] = {a4.x, a4.y, a4.z, a4.w};
        #pragma unroll
        for (int pi = 0; pi < 4; ++pi) {
            acc[pi][0].x = fmaf(ap[pi], w0.x, acc[pi][0].x);
            acc[pi][0].y = fmaf(ap[pi], w0.y, acc[pi][0].y);
            acc[pi][0].z = fmaf(ap[pi], w0.z, acc[pi][0].z);
            acc[pi][0].w = fmaf(ap[pi], w0.w, acc[pi][0].w);
            acc[pi][1].x = fmaf(ap[pi], w1.x, acc[pi][1].x);
            acc[pi][1].y = fmaf(ap[pi], w1.y, acc[pi][1].y);
            acc[pi][1].z = fmaf(ap[pi], w1.z, acc[pi][1].z);
            acc[pi][1].w = fmaf(ap[pi], w1.w, acc[pi][1].w);
        }
    }

    #pragma unroll
    for (int pi = 0; pi < 4; ++pi) {
        const size_t ob = ((size_t)b * HWs + s0 + 4 * p4 + pi) * CC + 8 * og;
        *reinterpret_cast<float4*>(Kf + ob)     = acc[pi][0];
        *reinterpret_cast<float4*>(Kf + ob + 4) = acc[pi][1];
    }
}

// ---------------------------------------------------------------------------
// Fused: query conv -> softmax -> (addr,weight) table -> sampling -> out.
// 256 thr, 32-px tile, batch = blockIdx&7 (batch<->XCD L2 locality).
// 6 blocks/CU (LDS 25.9 KB); sampling processes PIXEL PAIRS for 2x MLP.
// ---------------------------------------------------------------------------
__global__ __launch_bounds__(256, 6) void fused_sample_kernel(
    const float* __restrict__ query, const float* __restrict__ w_attn,
    const float* __restrict__ b_attn, const float* __restrict__ w_off,
    const float* __restrict__ b_off, const float* __restrict__ Kf,
    float* __restrict__ out)
{
    __shared__ float S[SM_LDS];
    float* Qin  = S + OFF_QIN;    // [64][32]
    float* Wq   = S + OFF_WQ;     // [64][20]
    float* Sb   = S + OFF_SB;     // [20]
    float* L    = S + OFF_L;      // [32][21]
    uint2* Tq   = reinterpret_cast<uint2*>(S + OFF_T);   // [32*9*4]
    float* OutT = S + OFF_QIN;    // [32][69] overlays Qin (dead after conv)

    const int t = threadIdx.x;
    const int l = t & 63;
    const int w = t >> 6;
    const int blk = blockIdx.x;
    const int b = blk & 7;                       // batch == XCD round-robin
    const int tile = blk >> 3;
    const int s0 = tile * SM_PX;
    const size_t qb = (size_t)b * CC * HWs + s0;
    const char* Kfb = reinterpret_cast<const char*>(Kf) + (size_t)b * HWs * CC * 4;

    // ---- stage query tile [k][px]
    #pragma unroll
    for (int m = 0; m < 2; ++m) {
        const int f = t + 256 * m;
        const int k = f >> 3;
        const int p4 = f & 7;
        *reinterpret_cast<float4*>(&Qin[k * 32 + 4 * p4]) =
            *reinterpret_cast<const float4*>(query + qb + (size_t)k * HWs + 4 * p4);
    }
    // ---- stage transposed query weights [k][20] + biases
    for (int f = t; f < 304; f += 256) {
        const int r = f >> 4;
        const int q = f & 15;
        const float* src = (r < KEYN) ? (w_attn + r * CC) : (w_off + (r - KEYN) * CC);
        const float4 wv = *reinterpret_cast<const float4*>(src + 4 * q);
        Wq[(4 * q + 0) * 20 + r] = wv.x;
        Wq[(4 * q + 1) * 20 + r] = wv.y;
        Wq[(4 * q + 2) * 20 + r] = wv.z;
        Wq[(4 * q + 3) * 20 + r] = wv.w;
    }
    if (t < 64) Wq[t * 20 + 19] = 0.f;
    if (t < 20) Sb[t] = (t < KEYN) ? b_attn[t] : (t < 19 ? b_off[t - KEYN] : 0.f);
    __syncthreads();

    // ---- query conv: thread = (px = t&31, og = t>>5 < 5)
    {
        const int px = t & 31;
        const int og = t >> 5;
        if (og < 5) {
            const int o4 = 4 * og;
            float4 acc = *reinterpret_cast<const float4*>(&Sb[o4]);
            #pragma unroll 8
            for (int k = 0; k < 64; ++k) {
                const float a = Qin[k * 32 + px];
                const float4 wv = *reinterpret_cast<const float4*>(&Wq[k * 20 + o4]);
                acc.x = fmaf(a, wv.x, acc.x);
                acc.y = fmaf(a, wv.y, acc.y);
                acc.z = fmaf(a, wv.z, acc.z);
                acc.w = fmaf(a, wv.w, acc.w);
            }
            L[px * 21 + o4 + 0] = acc.x;
            L[px * 21 + o4 + 1] = acc.y;
            L[px * 21 + o4 + 2] = acc.z;
            L[px * 21 + o4 + 3] = acc.w;
        }
    }
    __syncthreads();

    // ---- softmax in place: L[p][0..8] <- normalized attn
    if (t < SM_PX) {
        float lg[KEYN];
        #pragma unroll
        for (int k = 0; k < KEYN; ++k) lg[k] = L[t * 21 + k];
        float m = lg[0];
        #pragma unroll
        for (int k = 1; k < KEYN; ++k) m = fmaxf(m, lg[k]);
        float s = 0.f, e[KEYN];
        #pragma unroll
        for (int k = 0; k < KEYN; ++k) { e[k] = expf(lg[k] - m); s += e[k]; }
        const float sinv = 1.0f / s;
        #pragma unroll
        for (int k = 0; k < KEYN; ++k) L[t * 21 + k] = e[k] * sinv;
    }
    __syncthreads();

    // ---- table: (byte addr, wk = corner-weight * attn) per (px,key,corner)
    for (int f = t; f < SM_PX * KEYN * 4; f += 256) {
        const int p = f / 36;
        const int r = f - p * 36;
        const int k = r >> 2;
        const int g = r & 3;
        const int s = s0 + p;
        const int y = s / WW;
        const int x = s - y * WW;
        const float a  = L[p * 21 + k];
        const float dy = L[p * 21 + KEYN + k];
        const float dx = L[p * 21 + KEYN + k + 1];
        const float py = dy + (float)y;
        const float px = dx + (float)x;
        const float fy = floorf(py), fx = floorf(px);
        const int gdy = g >> 1, gdx = g & 1;
        const int iy = (int)fy + gdy;
        const int ix = (int)fx + gdx;
        const int yc = min(max(iy, 0), HH - 1);
        const int xc = min(max(ix, 0), WW - 1);
        const bool valid = (iy >= 0) & (iy < HH) & (ix >= 0) & (ix < WW);
        const float wy = gdy ? (py - fy) : (1.f - (py - fy));
        const float wx = gdx ? (px - fx) : (1.f - (px - fx));
        float wk = wy * wx * a;
        wk = valid ? wk : 0.f;
        const unsigned addr = (unsigned)((yc * WW + xc) * CC * 4);
        Tq[f] = make_uint2(addr, __float_as_uint(wk));
    }
    __syncthreads();

    // ---- sampling: wave w -> px [8w,8w+8) as 4 PAIRS (2 independent chains)
    const int g = l & 3;
    const int cb16 = (l >> 2) * 16;

    #pragma unroll
    for (int j = 0; j < 4; ++j) {
        const int p0 = w * 8 + 2 * j;
        const int p1 = p0 + 1;
        const uint2* Tp0 = Tq + p0 * 36 + g;
        const uint2* Tp1 = Tq + p1 * 36 + g;

        float4 a0 = make_float4(0.f, 0.f, 0.f, 0.f);
        float4 a1 = make_float4(0.f, 0.f, 0.f, 0.f);
        #pragma unroll
        for (int k = 0; k < KEYN; ++k) {
            const uint2 e0 = Tp0[k * 4];
            const uint2 e1 = Tp1[k * 4];
            const float4 v0 = *reinterpret_cast<const float4*>(Kfb + (e0.x + cb16));
            const float4 v1 = *reinterpret_cast<const float4*>(Kfb + (e1.x + cb16));
            const float w0 = __uint_as_float(e0.y);
            const float w1 = __uint_as_float(e1.y);
            a0.x = fmaf(v0.x, w0, a0.x); a0.y = fmaf(v0.y, w0, a0.y);
            a0.z = fmaf(v0.z, w0, a0.z); a0.w = fmaf(v0.w, w0, a0.w);
            a1.x = fmaf(v1.x, w1, a1.x); a1.y = fmaf(v1.y, w1, a1.y);
            a1.z = fmaf(v1.z, w1, a1.z); a1.w = fmaf(v1.w, w1, a1.w);
        }

        a0.x += swz1(a0.x); a0.y += swz1(a0.y); a0.z += swz1(a0.z); a0.w += swz1(a0.w);
        a1.x += swz1(a1.x); a1.y += swz1(a1.y); a1.z += swz1(a1.z); a1.w += swz1(a1.w);
        a0.x += swz2(a0.x); a0.y += swz2(a0.y); a0.z += swz2(a0.z); a0.w += swz2(a0.w);
        a1.x += swz2(a1.x); a1.y += swz2(a1.y); a1.z += swz2(a1.z); a1.w += swz2(a1.w);

        if (g == 0) {
            float* d0 = OutT + p0 * 69 + (cb16 >> 2);
            float* d1 = OutT + p1 * 69 + (cb16 >> 2);
            d0[0] = a0.x; d0[1] = a0.y; d0[2] = a0.z; d0[3] = a0.w;
            d1[0] = a1.x; d1[1] = a1.y; d1[2] = a1.z; d1[3] = a1.w;
        }
    }
    __syncthreads();

    // ---- transposed store: out[b][c][s0+px]
    const size_t ob = (size_t)b * CC * HWs + s0;
    #pragma unroll
    for (int m = 0; m < 8; ++m) {
        const int f = t + 256 * m;
        const int c = f >> 5;
        const int px = f & 31;
        out[ob + (size_t)c * HWs + px] = OutT[px * 69 + c];
    }
}

extern "C" void kernel_launch(void* const* d_in, const int* in_sizes, int n_in,
                              void* d_out, int out_size, void* d_ws, size_t ws_size,
                              hipStream_t stream)
{
    const float* query   = (const float*)d_in[0];
    const float* key     = (const float*)d_in[1];
    const float* w_refer = (const float*)d_in[2];
    const float* b_refer = (const float*)d_in[3];
    const float* w_attn  = (const float*)d_in[4];
    const float* b_attn  = (const float*)d_in[5];
    const float* w_off   = (const float*)d_in[6];
    const float* b_off   = (const float*)d_in[7];
    float* out = (float*)d_out;

    float* Kf = (float*)d_ws;   // [B*HW][64] pixel-major, 25.7 MB

    hipLaunchKernelGGL(conv_key_kernel, dim3(CK_NBLK), dim3(256), 0, stream,
                       key, w_refer, b_refer, Kf);
    hipLaunchKernelGGL(fused_sample_kernel, dim3(SM_NBLK), dim3(256), 0, stream,
                       query, w_attn, b_attn, w_off, b_off, Kf, out);
}